// Round 4
// baseline (357.794 us; speedup 1.0000x reference)
//
#include <hip/hip_runtime.h>
#include <stdint.h>

#define DIM 128
#define LN_EPS 1e-5f

static __device__ __forceinline__ float rlane(float v, int lane) {
    return __uint_as_float(
        (uint32_t)__builtin_amdgcn_readlane((int)__float_as_uint(v), lane));
}

// ---------------------------------------------------------------------------
// K1: degree + within-destination rank (the atomic's return value).
// ---------------------------------------------------------------------------
__global__ __launch_bounds__(256) void degree_rank_kernel(
    const int* __restrict__ ei, int* __restrict__ deg,
    int* __restrict__ rank, int E)
{
    int e = blockIdx.x * blockDim.x + threadIdx.x;
    if (e >= E) return;
    rank[e] = atomicAdd(deg + ei[E + e], 1);
}

// ---------------------------------------------------------------------------
// K2: single-block exclusive scan of deg -> offs. N=50k: each of 1024
// threads serially scans ~49 items, block-scan of partials, add back.
// ---------------------------------------------------------------------------
__global__ __launch_bounds__(1024) void scan_kernel(
    const int* __restrict__ deg, int* __restrict__ offs, int N)
{
    __shared__ int part[1024];
    int t = threadIdx.x;
    int C = (N + 1023) >> 10;
    int b0 = t * C;
    int s = 0;
    for (int i = 0; i < C; ++i) {
        int idx = b0 + i;
        if (idx < N) s += deg[idx];
    }
    part[t] = s;
    __syncthreads();
    for (int d = 1; d < 1024; d <<= 1) {
        int u = (t >= d) ? part[t - d] : 0;
        __syncthreads();
        part[t] += u;
        __syncthreads();
    }
    int run = part[t] - s;   // exclusive base for this thread's chunk
    for (int i = 0; i < C; ++i) {
        int idx = b0 + i;
        if (idx < N) { offs[idx] = run; run += deg[idx]; }
    }
}

// ---------------------------------------------------------------------------
// K3: fill CSR src lists — plain store at offs[dst] + rank[e], no atomics.
// ---------------------------------------------------------------------------
__global__ __launch_bounds__(256) void fill_kernel(
    const int* __restrict__ ei, const int* __restrict__ offs,
    const int* __restrict__ rank, int* __restrict__ src_list, int E)
{
    int e = blockIdx.x * blockDim.x + threadIdx.x;
    if (e >= E) return;
    src_list[offs[ei[E + e]] + rank[e]] = ei[e];
}

// ---------------------------------------------------------------------------
// K4: fused  mean-gather ; h = mean@W_l^T + b_l + x@W_r^T ; LayerNorm ; ReLU
// One wave per 8 rows; lane l owns output features {l, l+64}.
// Gather is interleaved across the 8 rows (8 independent load-FMA chains,
// ~16 loads in flight) with wave-uniform predication; chunked by 64
// neighbors so any degree is correct.
// ---------------------------------------------------------------------------
__global__ __launch_bounds__(256) void fused_kernel(
    const float* __restrict__ x,
    const int* __restrict__ offs,
    const int* __restrict__ deg,
    const int* __restrict__ src_list,
    const float* __restrict__ Wl,
    const float* __restrict__ bl,
    const float* __restrict__ Wr,
    const float* __restrict__ gma,
    const float* __restrict__ bta,
    float* __restrict__ out,
    int N)
{
    const int lane = threadIdx.x & 63;
    const int wave = blockIdx.x * (blockDim.x >> 6) + (threadIdx.x >> 6);
    const int row0 = wave * 8;
    if (row0 >= N) return;

    int off_s[8], dg_s[8];
    #pragma unroll
    for (int r = 0; r < 8; ++r) {
        int row = row0 + r;
        bool ok = (row < N);
        int rr = ok ? row : 0;
        off_s[r] = __builtin_amdgcn_readfirstlane(offs[rr]);
        dg_s[r]  = ok ? __builtin_amdgcn_readfirstlane(deg[rr]) : 0;
    }

    float m0[8], m1[8];
    #pragma unroll
    for (int r = 0; r < 8; ++r) { m0[r] = 0.0f; m1[r] = 0.0f; }

    for (int base = 0;; base += 64) {
        int nrem[8], mx = 0;
        #pragma unroll
        for (int r = 0; r < 8; ++r) {
            int t = dg_s[r] - base;
            t = (t < 0) ? 0 : (t > 64 ? 64 : t);
            nrem[r] = t;
            mx = (t > mx) ? t : mx;
        }
        if (mx == 0) break;

        int sidx[8];
        #pragma unroll
        for (int r = 0; r < 8; ++r)
            sidx[r] = (lane < nrem[r]) ? src_list[off_s[r] + base + lane] : 0;

        for (int j = 0; j < mx; ++j) {
            #pragma unroll
            for (int r = 0; r < 8; ++r) {
                float p = (j < nrem[r]) ? 1.0f : 0.0f;   // wave-uniform
                int s = __builtin_amdgcn_readlane(sidx[r], j);
                const float* xr = x + (size_t)s * DIM;
                m0[r] = fmaf(p, xr[lane], m0[r]);
                m1[r] = fmaf(p, xr[lane + 64], m1[r]);
            }
        }
    }

    // av[r][j] = a_row[j*64 + lane];  a = concat(mean, x), length 256
    float av[8][4];
    #pragma unroll
    for (int r = 0; r < 8; ++r) {
        int row = row0 + r;
        bool ok = (row < N);
        int rr = ok ? row : 0;
        float rc = (dg_s[r] > 0) ? (1.0f / (float)dg_s[r]) : 0.0f;
        const float* xw = x + (size_t)rr * DIM;
        av[r][0] = m0[r] * rc;
        av[r][1] = m1[r] * rc;
        av[r][2] = ok ? xw[lane] : 0.0f;
        av[r][3] = ok ? xw[lane + 64] : 0.0f;
    }

    const float bl0 = bl[lane];
    const float bl1 = bl[lane + 64];
    float acc0[8], acc1[8];
    #pragma unroll
    for (int r = 0; r < 8; ++r) { acc0[r] = bl0; acc1[r] = bl1; }

    const int d = lane;
    #pragma unroll
    for (int j = 0; j < 4; ++j) {
        const float* Wb = (j < 2) ? Wl : Wr;
        const float4* p0 = (const float4*)(Wb + (size_t)d * DIM + (j & 1) * 64);
        const float4* p1 = (const float4*)(Wb + (size_t)(d + 64) * DIM + (j & 1) * 64);
        #pragma unroll 4
        for (int q = 0; q < 16; ++q) {
            float4 w0 = p0[q];
            float4 w1 = p1[q];
            int kb = q * 4;
            #pragma unroll
            for (int r = 0; r < 8; ++r) {
                float a0 = rlane(av[r][j], kb + 0);
                float a1 = rlane(av[r][j], kb + 1);
                float a2 = rlane(av[r][j], kb + 2);
                float a3 = rlane(av[r][j], kb + 3);
                acc0[r] = fmaf(a0, w0.x, acc0[r]);
                acc1[r] = fmaf(a0, w1.x, acc1[r]);
                acc0[r] = fmaf(a1, w0.y, acc0[r]);
                acc1[r] = fmaf(a1, w1.y, acc1[r]);
                acc0[r] = fmaf(a2, w0.z, acc0[r]);
                acc1[r] = fmaf(a2, w1.z, acc1[r]);
                acc0[r] = fmaf(a3, w0.w, acc0[r]);
                acc1[r] = fmaf(a3, w1.w, acc1[r]);
            }
        }
    }

    const float g0 = gma[lane];
    const float g1 = gma[lane + 64];
    const float be0 = bta[lane];
    const float be1 = bta[lane + 64];

    #pragma unroll
    for (int r = 0; r < 8; ++r) {
        int row = row0 + r;
        if (row >= N) break;                       // wave-uniform
        float h0 = acc0[r], h1 = acc1[r];
        float s = h0 + h1;
        float q = h0 * h0 + h1 * h1;
        #pragma unroll
        for (int off = 32; off > 0; off >>= 1) {
            s += __shfl_xor(s, off, 64);
            q += __shfl_xor(q, off, 64);
        }
        float mu = s * (1.0f / 128.0f);
        float var = q * (1.0f / 128.0f) - mu * mu;
        float rs = rsqrtf(fmaxf(var, 0.0f) + LN_EPS);
        float o0 = fmaxf((h0 - mu) * rs * g0 + be0, 0.0f);
        float o1 = fmaxf((h1 - mu) * rs * g1 + be1, 0.0f);
        out[(size_t)row * DIM + lane] = o0;
        out[(size_t)row * DIM + lane + 64] = o1;
    }
}

extern "C" void kernel_launch(void* const* d_in, const int* in_sizes, int n_in,
                              void* d_out, int out_size, void* d_ws, size_t ws_size,
                              hipStream_t stream) {
    const float* x  = (const float*)d_in[0];
    const int* ei   = (const int*)d_in[1];
    const float* Wl = (const float*)d_in[2];
    const float* bl = (const float*)d_in[3];
    const float* Wr = (const float*)d_in[4];
    const float* ga = (const float*)d_in[5];
    const float* be = (const float*)d_in[6];
    float* out = (float*)d_out;

    int N = in_sizes[0] / DIM;   // 50000
    int E = in_sizes[1] / 2;     // 600000

    int* deg      = (int*)d_ws;
    int* offs     = deg + N;
    int* rank     = offs + N;
    int* src_list = rank + E;

    hipMemsetAsync(deg, 0, (size_t)N * sizeof(int), stream);

    degree_rank_kernel<<<(E + 255) / 256, 256, 0, stream>>>(ei, deg, rank, E);
    scan_kernel<<<1, 1024, 0, stream>>>(deg, offs, N);
    fill_kernel<<<(E + 255) / 256, 256, 0, stream>>>(ei, offs, rank, src_list, E);

    {
        int waves = (N + 7) / 8;
        int blocks = (waves + 3) / 4;
        fused_kernel<<<blocks, 256, 0, stream>>>(x, offs, deg, src_list,
                                                 Wl, bl, Wr, ga, be, out, N);
    }
}